// Round 12
// baseline (141.588 us; speedup 1.0000x reference)
//
#include <hip/hip_runtime.h>
#include <hip/hip_bf16.h>

#define NVOX 4096   // 16*16*16
#define CDIM 128

typedef __attribute__((ext_vector_type(8)))  short bf16x8;
typedef __attribute__((ext_vector_type(4)))  float f32x4;
typedef __attribute__((ext_vector_type(16))) float f32x16;

static __device__ __forceinline__ short f2bf(float f) {
    __hip_bfloat16 h = __float2bfloat16(f);
    union { __hip_bfloat16 h; short s; } u; u.h = h; return u.s;
}
// fast round-to-nearest bf16 pack for known-positive finite values (attn P path)
static __device__ __forceinline__ short f2bf_r(float f) {
    union { float f; unsigned u; } v; v.f = f;
    return (short)((v.u + 0x8000u) >> 16);
}
static __device__ __forceinline__ float bf2f(short s) {
    union { unsigned u; float f; } u;
    u.u = ((unsigned)(unsigned short)s) << 16;
    return u.f;
}
static __device__ __forceinline__ float fexp2(float x) {
    return __builtin_amdgcn_exp2f(x);
}
// MFMA K-fragment permutation for K=128 staging: packed position p <- channel ci
__device__ __forceinline__ int permpos(int ci) {
    return (((ci >> 2) & 3) << 3) + (ci & 3) + ((ci & 16) >> 2) + ((ci >> 5) << 5);
}
__device__ __forceinline__ int invp(int p) {
    const int c = p >> 5, r = p & 31, g = (r >> 3) & 3, j = r & 7;
    return (c << 5) + (j < 4 ? (g << 2) + j : 16 + (g << 2) + (j - 4));
}
// 16-element fragment permutation for 32x32x16 (K=16): pos(d)
__device__ __forceinline__ int pos16(int d) {
    return (d & 3) | ((d & 4) << 1) | ((d & 8) >> 1);
}

// ---------------- pack_all: coalesced LDS-transpose packs, one launch ----------------
// blocks: [0,64) pack_x | [64,87) xpad border zero | [87,215) pack_w1 |
//         [215,287) pack_wqkv | [287,319) pack_w2 | [319,684) zero xpad2
__global__ __launch_bounds__(256) void pack_all(
    const float* __restrict__ x,  const float* __restrict__ lw,
    const float* __restrict__ qw, const float* __restrict__ kw, const float* __restrict__ vw,
    const float* __restrict__ ow,
    short* __restrict__ xp, short* __restrict__ wb1, short* __restrict__ wqkv, short* __restrict__ wb2,
    short* __restrict__ xp2)
{
    __shared__ __align__(16) char sm[27904];
    const int b = blockIdx.x;
    const int tid = threadIdx.x;

    if (b < 64) {                                     // pack_x: 64 vox x 64 ch transpose
        float* lds = (float*)sm;                      // [64][65]
        const int n0 = b * 64;
        for (int i = tid; i < 4096; i += 256) {
            const int c = i >> 6, nl = i & 63;
            lds[nl * 65 + c] = x[c * NVOX + n0 + nl];
        }
        __syncthreads();
        for (int i = tid; i < 4096; i += 256) {
            const int nl = i >> 6, p = i & 63;
            const int n = n0 + nl;
            const int z = n >> 8, y = (n >> 4) & 15, xx = n & 15;
            const int vp = (z + 1) * 324 + (y + 1) * 18 + (xx + 1);
            xp[vp * 64 + p] = f2bf(lds[nl * 65 + invp(p)]);
        }
    } else if (b < 87) {                              // zero xpad borders
        const int vp = (b - 64) * 256 + tid;
        if (vp >= 5832) return;
        const int z = vp / 324, rem = vp - z * 324, y = rem / 18, xx = rem % 18;
        if (z >= 1 && z <= 16 && y >= 1 && y <= 16 && xx >= 1 && xx <= 16) return;
        const int4 z4 = {0, 0, 0, 0};
        int4* dst = (int4*)(xp + vp * 64);
        #pragma unroll
        for (int j = 0; j < 8; ++j) dst[j] = z4;
    } else if (b < 215) {                             // pack_w1: block per co
        float* lds = (float*)sm;                      // 1728
        const int co = b - 87;
        for (int i = tid; i < 1728; i += 256) lds[i] = lw[co * 1728 + i];
        __syncthreads();
        for (int i = tid; i < 1728; i += 256) {
            const int t = i >> 6, p = i & 63;
            wb1[t * 8192 + co * 64 + p] = f2bf(lds[invp(p) * 27 + t]);
        }
    } else if (b < 287) {                             // pack_wqkv: block per (l,m,co16)
        float* lds = (float*)sm;                      // 2048
        const int u = b - 215;
        const int l = u / 24, rm = u - l * 24;
        const int m = rm >> 3, cg = rm & 7;
        const int co0 = cg * 16;
        const float* W = (m == 0 ? qw : m == 1 ? kw : vw) + l * 16384;
        for (int i = tid; i < 2048; i += 256) {
            const int co_l = i >> 7, ci = i & 127;
            lds[i] = W[(co0 + co_l) * 128 + ci];
        }
        __syncthreads();
        for (int i = tid; i < 2048; i += 256) {
            const int co_l = i >> 7, p = i & 127;
            wqkv[((l * 3 + m) * 128 + co0 + co_l) * 128 + p] = f2bf(lds[co_l * 128 + invp(p)]);
        }
    } else if (b < 319) {                             // pack_w2: block per (ci16, co32)
        short* sld = (short*)sm;                      // [16][872]
        const int u = b - 287;
        const int ci_g = u >> 2, co_g = u & 3;
        const int ci0 = ci_g * 16, co0 = co_g * 32;
        for (int i = tid; i < 13824; i += 256) {
            const int ci_l = i / 864, r = i - ci_l * 864;
            sld[ci_l * 872 + r] = f2bf(ow[(ci0 + ci_l) * 3456 + co0 * 27 + r]);
        }
        __syncthreads();
        for (int i = tid; i < 13824; i += 256) {
            const int t = i >> 9, r2 = i & 511;
            const int co_l = r2 >> 4, ci_l = r2 & 15;
            wb2[t * 16384 + (co0 + co_l) * 128 + permpos(ci0 + ci_l)] =
                sld[ci_l * 872 + co_l * 27 + (26 - t)];
        }
    } else {                                          // zero xpad2
        const int e = (b - 319) * 256 + tid;
        if (e >= 5832 * 16) return;
        const int4 z4 = {0, 0, 0, 0};
        *reinterpret_cast<int4*>(xp2 + e * 8) = z4;
    }
}

// ---------------- conv1: LDS-halo MFMA. Block = 32co x 64vox, 4 waves ----------------
__global__ __launch_bounds__(256) void conv1_mfma(
    const short* __restrict__ xp,   // [5832][64perm]
    const short* __restrict__ wb,   // [27][128][64perm]
    const float* __restrict__ bias, const float* __restrict__ pos,
    short* __restrict__ latbf)
{
    __shared__ short bl[324 * 72];  // 18 lines x 18 x (64+8) shorts = 46.6 KB
    const int tid = threadIdx.x;
    const int g = blockIdx.x;
    const int cot = g >> 6;          // 0..3
    const int vgrp = g & 63;
    const int r0 = vgrp * 4;
    const int z = r0 >> 4, y0 = r0 & 15;

    for (int i = tid; i < 2592; i += 256) {
        const int col = i >> 3, pc = i & 7;            // 324 cols x 8 pieces
        const int line = col / 18, xq = col - line * 18;
        const int dz = line / 6, yi = line - dz * 6;
        const int4 v = *reinterpret_cast<const int4*>(
            xp + (((z + dz) * 18 + (y0 + yi)) * 18 + xq) * 64 + pc * 8);
        const int slot = ((((pc >> 2) ^ col) & 1) << 5) + ((pc & 3) << 3);
        *reinterpret_cast<int4*>(&bl[col * 72 + slot]) = v;
    }
    __syncthreads();

    const int wid = tid >> 6, lane = tid & 63;
    const int lg = lane >> 4, lq = lane & 15;
    const int wc = wid >> 1, wv = wid & 1;
    const int co0 = cot * 32 + wc * 16;

    const short* pA = wb + (co0 + lq) * 64 + lg * 8;

    auto ldA = [&](int t, bf16x8* A) {
        const short* p = pA + t * 8192;
        #pragma unroll
        for (int c = 0; c < 2; ++c) A[c] = *reinterpret_cast<const bf16x8*>(p + c * 32);
    };

    f32x4 acc0 = {0.f,0.f,0.f,0.f}, acc1 = {0.f,0.f,0.f,0.f};

    auto comp = [&](int t, const bf16x8* A) {
        const int dz = t / 9, r9 = t - dz * 9, dy = r9 / 3, dx = r9 - dy * 3;
        #pragma unroll
        for (int ry = 0; ry < 2; ++ry) {
            const int col = (dz * 6 + wv * 2 + ry + dy) * 18 + dx + lq;
            const short* bp = &bl[col * 72 + (lg << 3)];
            #pragma unroll
            for (int c = 0; c < 2; ++c) {
                const bf16x8 b = *reinterpret_cast<const bf16x8*>(bp + (((c ^ col) & 1) << 5));
                if (ry == 0) acc0 = __builtin_amdgcn_mfma_f32_16x16x32_bf16(A[c], b, acc0, 0, 0, 0);
                else         acc1 = __builtin_amdgcn_mfma_f32_16x16x32_bf16(A[c], b, acc1, 0, 0, 0);
            }
        }
    };

    bf16x8 A0[2], A1[2];
    int t = 0;
    ldA(0, A0);
    while (true) {
        if (t + 1 < 27) ldA(t + 1, A1);
        comp(t, A0);
        if (++t >= 27) break;
        if (t + 1 < 27) ldA(t + 1, A0);
        comp(t, A1);
        if (++t >= 27) break;
    }

    #pragma unroll
    for (int ry = 0; ry < 2; ++ry) {
        const f32x4 a = ry ? acc1 : acc0;
        const int n = (r0 + wv * 2 + ry) * 16 + lq;
        short4 s4;
        #pragma unroll
        for (int i = 0; i < 4; ++i) {
            const int co = co0 + 4 * lg + i;
            const float v = a[i] + bias[co] + pos[co * NVOX + n];
            ((short*)&s4)[i] = f2bf(v);
        }
        *reinterpret_cast<short4*>(latbf + n * 128 + permpos(co0 + 4 * lg)) = s4;
    }
}

// ---------------- proj: 3x GEMM 128x4096x128; A in regs, 2 row-tiles/wave ----------------
__global__ __launch_bounds__(256) void proj_mfma(
    const short* __restrict__ latbf,     // [4096][128perm]
    const short* __restrict__ wl,        // [3][128][128perm] (this layer)
    const float* __restrict__ bq, const float* __restrict__ bk, const float* __restrict__ bv,
    short* __restrict__ qP, short* __restrict__ kP, short* __restrict__ vP)
{
    const int m = blockIdx.z;
    const int wid = threadIdx.x >> 6, lane = threadIdx.x & 63;
    const int lg = lane >> 4, lq = lane & 15;
    const int co0 = blockIdx.y * 16;
    const int row0 = (blockIdx.x * 4 + wid) * 2;

    const short* A = wl + m * 16384 + (co0 + lq) * 128 + lg * 8;
    bf16x8 Af[4];
    #pragma unroll
    for (int c = 0; c < 4; ++c) Af[c] = *reinterpret_cast<const bf16x8*>(A + c * 32);

    const short* Bp0 = latbf + (row0 * 16 + lq) * 128 + lg * 8;
    const short* Bp1 = Bp0 + 16 * 128;
    bf16x8 Bf0[4], Bf1[4];
    #pragma unroll
    for (int c = 0; c < 4; ++c) Bf0[c] = *reinterpret_cast<const bf16x8*>(Bp0 + c * 32);
    #pragma unroll
    for (int c = 0; c < 4; ++c) Bf1[c] = *reinterpret_cast<const bf16x8*>(Bp1 + c * 32);

    f32x4 a0a = {0.f,0.f,0.f,0.f}, a0b = a0a, a1a = a0a, a1b = a0a;
    a0a = __builtin_amdgcn_mfma_f32_16x16x32_bf16(Af[0], Bf0[0], a0a, 0, 0, 0);
    a1a = __builtin_amdgcn_mfma_f32_16x16x32_bf16(Af[0], Bf1[0], a1a, 0, 0, 0);
    a0b = __builtin_amdgcn_mfma_f32_16x16x32_bf16(Af[1], Bf0[1], a0b, 0, 0, 0);
    a1b = __builtin_amdgcn_mfma_f32_16x16x32_bf16(Af[1], Bf1[1], a1b, 0, 0, 0);
    a0a = __builtin_amdgcn_mfma_f32_16x16x32_bf16(Af[2], Bf0[2], a0a, 0, 0, 0);
    a1a = __builtin_amdgcn_mfma_f32_16x16x32_bf16(Af[2], Bf1[2], a1a, 0, 0, 0);
    a0b = __builtin_amdgcn_mfma_f32_16x16x32_bf16(Af[3], Bf0[3], a0b, 0, 0, 0);
    a1b = __builtin_amdgcn_mfma_f32_16x16x32_bf16(Af[3], Bf1[3], a1b, 0, 0, 0);

    const int h = blockIdx.y;
    #pragma unroll
    for (int rr = 0; rr < 2; ++rr) {
        const f32x4 acc = rr ? (a1a + a1b) : (a0a + a0b);
        const int row = row0 + rr;
        const int n = row * 16 + lq;
        if (m == 2) {
            const int col = row * 16 + pos16(lq);
            #pragma unroll
            for (int r = 0; r < 4; ++r) {
                const int d = lg * 4 + r;
                vP[(h * 17 + d) * NVOX + col] = f2bf(acc[r] + bv[co0 + d]);
            }
            if (lg == 0) vP[(h * 17 + 16) * NVOX + col] = (short)0x3F80;  // bf16 1.0
        } else {
            const float* bias = (m == 0) ? bq : bk;
            const float S = (m == 0) ? 0.25f * 1.4426950408889634f : 1.f;
            const int pg = ((lg & 1) << 3) | ((lg & 2) << 1);   // pos16(lg*4)
            short4 s4;
            #pragma unroll
            for (int r = 0; r < 4; ++r) {
                const int co = co0 + lg * 4 + r;
                ((short*)&s4)[r] = f2bf((acc[r] + bias[co]) * S);
            }
            short* dst = (m == 0) ? qP : kP;
            *reinterpret_cast<short4*>(dst + ((h << 12) + n) * 16 + pg) = s4;
        }
    }
}

// ---------------- attn: 32x32x16 MFMA, no-max softmax, 8 waves = 2 qgrp x 4 ksplit ----------------
__global__ __launch_bounds__(512) void attn_mfma(
    const short* __restrict__ qP, const short* __restrict__ kP, const short* __restrict__ vP,
    short* __restrict__ latbf, short* __restrict__ outbf,
    const float* __restrict__ gamma, int layer, int last)
{
    __shared__ float smO[8][64][17];
    const int tid = threadIdx.x;
    const int wid = tid >> 6, lane = tid & 63;
    const int l5 = lane >> 5, lm = lane & 31;
    const int qg = wid >> 2, ksp = wid & 3;
    const int h = blockIdx.y;
    const int qbase = blockIdx.x * 128 + qg * 64;

    const bf16x8 qf0 = *reinterpret_cast<const bf16x8*>(
        qP + (((h << 12) + qbase + lm) << 4) + l5 * 8);
    const bf16x8 qf1 = *reinterpret_cast<const bf16x8*>(
        qP + (((h << 12) + qbase + 32 + lm) << 4) + l5 * 8);

    const short* kbase = kP + (((size_t)h) << 16);       // h*4096*16
    const int vrow = (lm & 16) ? 16 : lm;
    const short* vbase = vP + ((size_t)h * 17 + vrow) * NVOX + l5 * 8;

    f32x16 acc0 = {0.f,0.f,0.f,0.f,0.f,0.f,0.f,0.f,0.f,0.f,0.f,0.f,0.f,0.f,0.f,0.f};
    f32x16 acc1 = acc0;
    const f32x16 zero = acc0;

    bf16x8 kfA, v0A, v1A, kfB, v0B, v1B;
    auto LD = [&](int kc, bf16x8& kf, bf16x8& v0, bf16x8& v1) {
        kf = *reinterpret_cast<const bf16x8*>(kbase + ((kc + lm) << 4) + l5 * 8);
        v0 = *reinterpret_cast<const bf16x8*>(vbase + kc);
        v1 = *reinterpret_cast<const bf16x8*>(vbase + kc + 16);
    };
    auto COMP = [&](const bf16x8& kf, const bf16x8& v0, const bf16x8& v1) {
        const f32x16 S0 = __builtin_amdgcn_mfma_f32_32x32x16_bf16(kf, qf0, zero, 0, 0, 0);
        const f32x16 S1 = __builtin_amdgcn_mfma_f32_32x32x16_bf16(kf, qf1, zero, 0, 0, 0);
        short p0[16], p1[16];
        #pragma unroll
        for (int r = 0; r < 16; ++r) p0[r] = f2bf_r(fexp2(S0[r]));
        #pragma unroll
        for (int r = 0; r < 16; ++r) p1[r] = f2bf_r(fexp2(S1[r]));
        const bf16x8 pa00 = {p0[0],p0[1],p0[2],p0[3],p0[4],p0[5],p0[6],p0[7]};
        const bf16x8 pa01 = {p0[8],p0[9],p0[10],p0[11],p0[12],p0[13],p0[14],p0[15]};
        const bf16x8 pa10 = {p1[0],p1[1],p1[2],p1[3],p1[4],p1[5],p1[6],p1[7]};
        const bf16x8 pa11 = {p1[8],p1[9],p1[10],p1[11],p1[12],p1[13],p1[14],p1[15]};
        acc0 = __builtin_amdgcn_mfma_f32_32x32x16_bf16(pa00, v0, acc0, 0, 0, 0);
        acc0 = __builtin_amdgcn_mfma_f32_32x32x16_bf16(pa01, v1, acc0, 0, 0, 0);
        acc1 = __builtin_amdgcn_mfma_f32_32x32x16_bf16(pa10, v0, acc1, 0, 0, 0);
        acc1 = __builtin_amdgcn_mfma_f32_32x32x16_bf16(pa11, v1, acc1, 0, 0, 0);
    };

    int kc = ksp * 1024;
    int it = 0;
    LD(kc, kfA, v0A, v1A);
    while (true) {
        if (it + 1 < 32) LD(kc + 32, kfB, v0B, v1B);
        COMP(kfA, v0A, v1A);
        kc += 32;
        if (++it >= 32) break;
        if (it + 1 < 32) LD(kc + 32, kfA, v0A, v1A);
        COMP(kfB, v0B, v1B);
        kc += 32;
        if (++it >= 32) break;
    }

    if (lm <= 16) {
        #pragma unroll
        for (int r = 0; r < 16; ++r) {
            const int qrow = (r & 3) + 8 * (r >> 2) + 4 * l5;
            smO[wid][qrow][lm]      = acc0[r];
            smO[wid][32 + qrow][lm] = acc1[r];
        }
    }
    __syncthreads();

    // 512 threads finalize 128q x 16d: combine 4 k-splits per q-group, normalize, residual
    const int q = tid >> 2;                  // 0..127
    const int d0 = (tid & 3) * 4;
    const int g4 = (q >> 6) * 4, ql = q & 63;
    const float ls = smO[g4][ql][16] + smO[g4+1][ql][16] + smO[g4+2][ql][16] + smO[g4+3][ql][16];
    const float ginv = gamma[layer] / ls;
    const int n = blockIdx.x * 128 + q;
    const int c0 = (h << 4) + d0;
    const short4 r4 = *reinterpret_cast<const short4*>(latbf + n * 128 + permpos(c0));
    short4 s4;
    #pragma unroll
    for (int dd = 0; dd < 4; ++dd) {
        const int d = d0 + dd;
        const float Ov = smO[g4][ql][d] + smO[g4+1][ql][d] + smO[g4+2][ql][d] + smO[g4+3][ql][d];
        const float val = Ov * ginv + bf2f(((const short*)&r4)[dd]);
        ((short*)&s4)[dd] = f2bf(val);
    }
    if (!last) {
        *reinterpret_cast<short4*>(latbf + n * 128 + permpos(c0)) = s4;
    } else {
        const int zq = n >> 8, yq = (n >> 4) & 15, xq = n & 15;
        const int vp = (zq + 1) * 324 + (yq + 1) * 18 + (xq + 1);
        *reinterpret_cast<short4*>(outbf + vp * 128 + permpos(c0)) = s4;
    }
}

// ---------------- conv2: LDS-halo MFMA. Block = 32co x 64vox, 4 waves ----------------
__global__ __launch_bounds__(256) void conv2_mfma(
    const short* __restrict__ xp,   // [5832][128perm]
    const short* __restrict__ wb,   // [27][128co][128perm]
    const float* __restrict__ bias,
    float* __restrict__ out)
{
    __shared__ short bl[324 * 136];  // 18 lines x 18 x (128+8) shorts = 88.1 KB
    const int tid = threadIdx.x;
    const int g = blockIdx.x;
    const int cot = g >> 6;          // 0..3
    const int vgrp = g & 63;
    const int r0 = vgrp * 4;
    const int z = r0 >> 4, y0 = r0 & 15;

    for (int i = tid; i < 5184; i += 256) {
        const int col = i >> 4, pc = i & 15;           // 324 cols x 16 pieces
        const int line = col / 18, xq = col - line * 18;
        const int dz = line / 6, yi = line - dz * 6;
        const int4 v = *reinterpret_cast<const int4*>(
            xp + (((z + dz) * 18 + (y0 + yi)) * 18 + xq) * 128 + pc * 8);
        const int slot = ((((pc >> 2) ^ col) & 3) << 5) + ((pc & 3) << 3);
        *reinterpret_cast<int4*>(&bl[col * 136 + slot]) = v;
    }
    __syncthreads();

    const int wid = tid >> 6, lane = tid & 63;
    const int lg = lane >> 4, lq = lane & 15;
    const int wc = wid >> 1, wv = wid & 1;
    const int co0 = cot * 32 + wc * 16;

    const short* pA = wb + (co0 + lq) * 128 + lg * 8;

    auto ldA = [&](int t, bf16x8* A) {
        const short* p = pA + t * 16384;
        #pragma unroll
        for (int c = 0; c < 4; ++c) A[c] = *reinterpret_cast<const bf16x8*>(p + c * 32);
    };

    f32x4 acc0 = {0.f,0.f,0.f,0.f}, acc1 = {0.f,0.f,0.f,0.f};

    auto comp = [&](int t, const bf16x8* A) {
        const int dz = t / 9, r9 = t - dz * 9, dy = r9 / 3, dx = r9 - dy * 3;
        #pragma unroll
        for (int ry = 0; ry < 2; ++ry) {
            const int col = (dz * 6 + wv * 2 + ry + dy) * 18 + dx + lq;
            const short* bp = &bl[col * 136 + (lg << 3)];
            #pragma unroll
            for (int c = 0; c < 4; ++c) {
                const bf16x8 b = *reinterpret_cast<const bf16x8*>(bp + (((c ^ col) & 3) << 5));
                if (ry == 0) acc0 = __builtin_amdgcn_mfma_f32_16x16x32_bf16(A[c], b, acc0, 0, 0, 0);
                else         acc1 = __builtin_amdgcn_mfma_f32_16x16x32_bf16(A[c], b, acc1, 0, 0, 0);
            }
        }
    };

    bf16x8 A0[4], A1[4];
    int t = 0;
    ldA(0, A0);
    while (true) {
        if (t + 1 < 27) ldA(t + 1, A1);
        comp(t, A0);
        if (++t >= 27) break;
        if (t + 1 < 27) ldA(t + 1, A0);
        comp(t, A1);
        if (++t >= 27) break;
    }

    #pragma unroll
    for (int ry = 0; ry < 2; ++ry) {
        const f32x4 a = ry ? acc1 : acc0;
        const int n = (r0 + wv * 2 + ry) * 16 + lq;
        #pragma unroll
        for (int i = 0; i < 4; ++i) {
            const int co = co0 + 4 * lg + i;
            out[co * NVOX + n] = a[i] + bias[co];
        }
    }
}

extern "C" void kernel_launch(void* const* d_in, const int* in_sizes, int n_in,
                              void* d_out, int out_size, void* d_ws, size_t ws_size,
                              hipStream_t stream) {
    const float* x     = (const float*)d_in[0];
    const float* lw    = (const float*)d_in[1];
    const float* lb    = (const float*)d_in[2];
    const float* pos   = (const float*)d_in[3];
    const float* qw    = (const float*)d_in[4];
    const float* qb    = (const float*)d_in[5];
    const float* kw    = (const float*)d_in[6];
    const float* kb    = (const float*)d_in[7];
    const float* vw    = (const float*)d_in[8];
    const float* vb    = (const float*)d_in[9];
    const float* gamma = (const float*)d_in[10];
    const float* ow    = (const float*)d_in[11];
    const float* ob    = (const float*)d_in[12];

    short* latbf = (short*)d_ws;                 // 524288 sh
    short* qP    = latbf + 524288;               // 524288 sh
    short* kP    = qP + 524288;                  // 524288 sh
    short* vP    = kP + 524288;                  // 557056 sh (8*17*4096)
    short* xpad  = vP + 557056;                  // 373248 sh (conv1 input)
    short* xpad2 = xpad + 373248;                // 746496 sh (conv2 input)
    short* wbf1  = xpad2 + 746496;               // 221184 sh
    short* wqkv  = wbf1 + 221184;                // 442368 sh
    short* wbf2  = wqkv + 442368;                // 442368 sh

    pack_all<<<684, 256, 0, stream>>>(x, lw, qw, kw, vw, ow, xpad, wbf1, wqkv, wbf2, xpad2);

    conv1_mfma<<<256, 256, 0, stream>>>(xpad, wbf1, lb, pos, latbf);

    for (int i = 0; i < 3; ++i) {
        const int last = (i == 2);
        proj_mfma<<<dim3(32, 8, 3), 256, 0, stream>>>(
            latbf, wqkv + i * 49152, qb + i * 128, kb + i * 128, vb + i * 128, qP, kP, vP);
        attn_mfma<<<dim3(32, 8), 512, 0, stream>>>(
            qP, kP, vP, latbf, last ? xpad2 : latbf, gamma, i, last);
    }

    conv2_mfma<<<256, 256, 0, stream>>>(xpad2, wbf2, ob, (float*)d_out);
}

// Round 13
// 135.573 us; speedup vs baseline: 1.0444x; 1.0444x over previous
//
#include <hip/hip_runtime.h>
#include <hip/hip_bf16.h>

#define NVOX 4096   // 16*16*16
#define CDIM 128

typedef __attribute__((ext_vector_type(8)))  short bf16x8;
typedef __attribute__((ext_vector_type(4)))  float f32x4;
typedef __attribute__((ext_vector_type(16))) float f32x16;

static __device__ __forceinline__ short f2bf(float f) {
    __hip_bfloat16 h = __float2bfloat16(f);
    union { __hip_bfloat16 h; short s; } u; u.h = h; return u.s;
}
// fast round-to-nearest bf16 pack for known-positive finite values (attn P path)
static __device__ __forceinline__ short f2bf_r(float f) {
    union { float f; unsigned u; } v; v.f = f;
    return (short)((v.u + 0x8000u) >> 16);
}
static __device__ __forceinline__ float bf2f(short s) {
    union { unsigned u; float f; } u;
    u.u = ((unsigned)(unsigned short)s) << 16;
    return u.f;
}
static __device__ __forceinline__ float fexp2(float x) {
    return __builtin_amdgcn_exp2f(x);
}
// MFMA K-fragment permutation for K=128 staging: packed position p <- channel ci
__device__ __forceinline__ int permpos(int ci) {
    return (((ci >> 2) & 3) << 3) + (ci & 3) + ((ci & 16) >> 2) + ((ci >> 5) << 5);
}
__device__ __forceinline__ int invp(int p) {
    const int c = p >> 5, r = p & 31, g = (r >> 3) & 3, j = r & 7;
    return (c << 5) + (j < 4 ? (g << 2) + j : 16 + (g << 2) + (j - 4));
}
// 16-element fragment permutation for 32x32x16 (K=16): pos(d)
__device__ __forceinline__ int pos16(int d) {
    return (d & 3) | ((d & 4) << 1) | ((d & 8) >> 1);
}

// ---------------- pack_all: weight/input packs + xpad2 zeroing, one launch ----------------
__global__ __launch_bounds__(256) void pack_all(
    const float* __restrict__ x,  const float* __restrict__ lw,
    const float* __restrict__ qw, const float* __restrict__ kw, const float* __restrict__ vw,
    const float* __restrict__ ow,
    short* __restrict__ xp, short* __restrict__ wb1, short* __restrict__ wqkv, short* __restrict__ wb2,
    short* __restrict__ xp2)
{
    const int b = blockIdx.x;
    const int tid = threadIdx.x;
    if (b < 1458) {                                   // pack_x
        const int e = b * 256 + tid;
        if (e >= 5832 * 64) return;
        const int vp = e >> 6, p = e & 63;
        const int z = vp / 324, rem = vp - z * 324, y = rem / 18, xx = rem % 18;
        short val = 0;
        if (z >= 1 && z <= 16 && y >= 1 && y <= 16 && xx >= 1 && xx <= 16) {
            const int n = ((z - 1) * 16 + (y - 1)) * 16 + (xx - 1);
            val = f2bf(x[invp(p) * NVOX + n]);
        }
        xp[e] = val;
    } else if (b < 1458 + 864) {                      // pack_w1
        const int e = (b - 1458) * 256 + tid;
        if (e >= 27 * 128 * 64) return;
        const int t = e >> 13, co = (e >> 6) & 127, p = e & 63;
        wb1[e] = f2bf(lw[(co * 64 + invp(p)) * 27 + t]);
    } else if (b < 1458 + 864 + 576) {                // pack_wqkv
        const int e = (b - 2322) * 256 + tid;
        if (e >= 3 * 3 * 128 * 128) return;
        const int l = e / 49152, r = e - l * 49152;
        const int m = r >> 14, co = (r >> 7) & 127, p = r & 127;
        const float* W = (m == 0 ? qw : m == 1 ? kw : vw) + l * 16384;
        wqkv[e] = f2bf(W[co * 128 + invp(p)]);
    } else if (b < 1458 + 864 + 576 + 1728) {         // pack_w2
        const int e = (b - 2898) * 256 + tid;
        if (e >= 27 * 128 * 128) return;
        const int t = e >> 14, co = (e >> 7) & 127, p = e & 127;
        wb2[e] = f2bf(ow[(invp(p) * 128 + co) * 27 + (26 - t)]);
    } else {                                          // zero xpad2 (borders; interior rewritten by attn L2)
        const int e = (b - 4626) * 256 + tid;
        if (e >= 5832 * 16) return;
        const int4 z4 = {0, 0, 0, 0};
        *reinterpret_cast<int4*>(xp2 + e * 8) = z4;
    }
}

// ---------------- conv1: LDS-halo MFMA. Block = 32co x 64vox, 4 waves ----------------
__global__ __launch_bounds__(256) void conv1_mfma(
    const short* __restrict__ xp,   // [5832][64perm]
    const short* __restrict__ wb,   // [27][128][64perm]
    const float* __restrict__ bias, const float* __restrict__ pos,
    short* __restrict__ latbf)
{
    __shared__ short bl[324 * 72];  // 18 lines x 18 x (64+8) shorts = 46.6 KB
    const int tid = threadIdx.x;
    const int g = blockIdx.x;
    const int cot = g >> 6;          // 0..3
    const int vgrp = g & 63;
    const int r0 = vgrp * 4;
    const int z = r0 >> 4, y0 = r0 & 15;

    for (int i = tid; i < 2592; i += 256) {
        const int col = i >> 3, pc = i & 7;            // 324 cols x 8 pieces
        const int line = col / 18, xq = col - line * 18;
        const int dz = line / 6, yi = line - dz * 6;
        const int4 v = *reinterpret_cast<const int4*>(
            xp + (((z + dz) * 18 + (y0 + yi)) * 18 + xq) * 64 + pc * 8);
        const int slot = ((((pc >> 2) ^ col) & 1) << 5) + ((pc & 3) << 3);
        *reinterpret_cast<int4*>(&bl[col * 72 + slot]) = v;
    }
    __syncthreads();

    const int wid = tid >> 6, lane = tid & 63;
    const int lg = lane >> 4, lq = lane & 15;
    const int wc = wid >> 1, wv = wid & 1;
    const int co0 = cot * 32 + wc * 16;

    const short* pA = wb + (co0 + lq) * 64 + lg * 8;

    auto ldA = [&](int t, bf16x8* A) {
        const short* p = pA + t * 8192;
        #pragma unroll
        for (int c = 0; c < 2; ++c) A[c] = *reinterpret_cast<const bf16x8*>(p + c * 32);
    };

    f32x4 acc0 = {0.f,0.f,0.f,0.f}, acc1 = {0.f,0.f,0.f,0.f};

    auto comp = [&](int t, const bf16x8* A) {
        const int dz = t / 9, r9 = t - dz * 9, dy = r9 / 3, dx = r9 - dy * 3;
        #pragma unroll
        for (int ry = 0; ry < 2; ++ry) {
            const int col = (dz * 6 + wv * 2 + ry + dy) * 18 + dx + lq;
            const short* bp = &bl[col * 72 + (lg << 3)];
            #pragma unroll
            for (int c = 0; c < 2; ++c) {
                const bf16x8 b = *reinterpret_cast<const bf16x8*>(bp + (((c ^ col) & 1) << 5));
                if (ry == 0) acc0 = __builtin_amdgcn_mfma_f32_16x16x32_bf16(A[c], b, acc0, 0, 0, 0);
                else         acc1 = __builtin_amdgcn_mfma_f32_16x16x32_bf16(A[c], b, acc1, 0, 0, 0);
            }
        }
    };

    bf16x8 A0[2], A1[2];
    int t = 0;
    ldA(0, A0);
    while (true) {
        if (t + 1 < 27) ldA(t + 1, A1);
        comp(t, A0);
        if (++t >= 27) break;
        if (t + 1 < 27) ldA(t + 1, A0);
        comp(t, A1);
        if (++t >= 27) break;
    }

    #pragma unroll
    for (int ry = 0; ry < 2; ++ry) {
        const f32x4 a = ry ? acc1 : acc0;
        const int n = (r0 + wv * 2 + ry) * 16 + lq;
        short4 s4;
        #pragma unroll
        for (int i = 0; i < 4; ++i) {
            const int co = co0 + 4 * lg + i;
            const float v = a[i] + bias[co] + pos[co * NVOX + n];
            ((short*)&s4)[i] = f2bf(v);
        }
        *reinterpret_cast<short4*>(latbf + n * 128 + permpos(co0 + 4 * lg)) = s4;
    }
}

// ---------------- proj: 3x GEMM 128x4096x128; A in regs, 2 row-tiles/wave ----------------
__global__ __launch_bounds__(256) void proj_mfma(
    const short* __restrict__ latbf,     // [4096][128perm]
    const short* __restrict__ wl,        // [3][128][128perm] (this layer)
    const float* __restrict__ bq, const float* __restrict__ bk, const float* __restrict__ bv,
    short* __restrict__ qP, short* __restrict__ kP, short* __restrict__ vP)
{
    const int m = blockIdx.z;
    const int wid = threadIdx.x >> 6, lane = threadIdx.x & 63;
    const int lg = lane >> 4, lq = lane & 15;
    const int co0 = blockIdx.y * 16;
    const int row0 = (blockIdx.x * 4 + wid) * 2;

    const short* A = wl + m * 16384 + (co0 + lq) * 128 + lg * 8;
    bf16x8 Af[4];
    #pragma unroll
    for (int c = 0; c < 4; ++c) Af[c] = *reinterpret_cast<const bf16x8*>(A + c * 32);

    const short* Bp0 = latbf + (row0 * 16 + lq) * 128 + lg * 8;
    const short* Bp1 = Bp0 + 16 * 128;
    bf16x8 Bf0[4], Bf1[4];
    #pragma unroll
    for (int c = 0; c < 4; ++c) Bf0[c] = *reinterpret_cast<const bf16x8*>(Bp0 + c * 32);
    #pragma unroll
    for (int c = 0; c < 4; ++c) Bf1[c] = *reinterpret_cast<const bf16x8*>(Bp1 + c * 32);

    f32x4 a0a = {0.f,0.f,0.f,0.f}, a0b = a0a, a1a = a0a, a1b = a0a;
    a0a = __builtin_amdgcn_mfma_f32_16x16x32_bf16(Af[0], Bf0[0], a0a, 0, 0, 0);
    a1a = __builtin_amdgcn_mfma_f32_16x16x32_bf16(Af[0], Bf1[0], a1a, 0, 0, 0);
    a0b = __builtin_amdgcn_mfma_f32_16x16x32_bf16(Af[1], Bf0[1], a0b, 0, 0, 0);
    a1b = __builtin_amdgcn_mfma_f32_16x16x32_bf16(Af[1], Bf1[1], a1b, 0, 0, 0);
    a0a = __builtin_amdgcn_mfma_f32_16x16x32_bf16(Af[2], Bf0[2], a0a, 0, 0, 0);
    a1a = __builtin_amdgcn_mfma_f32_16x16x32_bf16(Af[2], Bf1[2], a1a, 0, 0, 0);
    a0b = __builtin_amdgcn_mfma_f32_16x16x32_bf16(Af[3], Bf0[3], a0b, 0, 0, 0);
    a1b = __builtin_amdgcn_mfma_f32_16x16x32_bf16(Af[3], Bf1[3], a1b, 0, 0, 0);

    const int h = blockIdx.y;
    #pragma unroll
    for (int rr = 0; rr < 2; ++rr) {
        const f32x4 acc = rr ? (a1a + a1b) : (a0a + a0b);
        const int row = row0 + rr;
        const int n = row * 16 + lq;
        if (m == 2) {
            const int col = row * 16 + pos16(lq);
            #pragma unroll
            for (int r = 0; r < 4; ++r) {
                const int d = lg * 4 + r;
                vP[(h * 17 + d) * NVOX + col] = f2bf(acc[r] + bv[co0 + d]);
            }
            if (lg == 0) vP[(h * 17 + 16) * NVOX + col] = (short)0x3F80;  // bf16 1.0
        } else {
            const float* bias = (m == 0) ? bq : bk;
            const float S = (m == 0) ? 0.25f * 1.4426950408889634f : 1.f;
            const int pg = ((lg & 1) << 3) | ((lg & 2) << 1);   // pos16(lg*4)
            short4 s4;
            #pragma unroll
            for (int r = 0; r < 4; ++r) {
                const int co = co0 + lg * 4 + r;
                ((short*)&s4)[r] = f2bf((acc[r] + bias[co]) * S);
            }
            short* dst = (m == 0) ? qP : kP;
            *reinterpret_cast<short4*>(dst + ((h << 12) + n) * 16 + pg) = s4;
        }
    }
}

// ---------------- attn: 32x32x16 MFMA, no-max softmax, 8 waves = 2 qgrp x 4 ksplit ----------------
__global__ __launch_bounds__(512) void attn_mfma(
    const short* __restrict__ qP, const short* __restrict__ kP, const short* __restrict__ vP,
    short* __restrict__ latbf, short* __restrict__ outbf,
    const float* __restrict__ gamma, int layer, int last)
{
    __shared__ float smO[8][64][17];
    const int tid = threadIdx.x;
    const int wid = tid >> 6, lane = tid & 63;
    const int l5 = lane >> 5, lm = lane & 31;
    const int qg = wid >> 2, ksp = wid & 3;
    const int h = blockIdx.y;
    const int qbase = blockIdx.x * 128 + qg * 64;

    const bf16x8 qf0 = *reinterpret_cast<const bf16x8*>(
        qP + (((h << 12) + qbase + lm) << 4) + l5 * 8);
    const bf16x8 qf1 = *reinterpret_cast<const bf16x8*>(
        qP + (((h << 12) + qbase + 32 + lm) << 4) + l5 * 8);

    const short* kbase = kP + (((size_t)h) << 16);       // h*4096*16
    const int vrow = (lm & 16) ? 16 : lm;
    const short* vbase = vP + ((size_t)h * 17 + vrow) * NVOX + l5 * 8;

    f32x16 acc0 = {0.f,0.f,0.f,0.f,0.f,0.f,0.f,0.f,0.f,0.f,0.f,0.f,0.f,0.f,0.f,0.f};
    f32x16 acc1 = acc0;
    const f32x16 zero = acc0;

    bf16x8 kfA, v0A, v1A, kfB, v0B, v1B;
    auto LD = [&](int kc, bf16x8& kf, bf16x8& v0, bf16x8& v1) {
        kf = *reinterpret_cast<const bf16x8*>(kbase + ((kc + lm) << 4) + l5 * 8);
        v0 = *reinterpret_cast<const bf16x8*>(vbase + kc);
        v1 = *reinterpret_cast<const bf16x8*>(vbase + kc + 16);
    };
    auto COMP = [&](const bf16x8& kf, const bf16x8& v0, const bf16x8& v1) {
        const f32x16 S0 = __builtin_amdgcn_mfma_f32_32x32x16_bf16(kf, qf0, zero, 0, 0, 0);
        const f32x16 S1 = __builtin_amdgcn_mfma_f32_32x32x16_bf16(kf, qf1, zero, 0, 0, 0);
        short p0[16], p1[16];
        #pragma unroll
        for (int r = 0; r < 16; ++r) p0[r] = f2bf_r(fexp2(S0[r]));
        #pragma unroll
        for (int r = 0; r < 16; ++r) p1[r] = f2bf_r(fexp2(S1[r]));
        const bf16x8 pa00 = {p0[0],p0[1],p0[2],p0[3],p0[4],p0[5],p0[6],p0[7]};
        const bf16x8 pa01 = {p0[8],p0[9],p0[10],p0[11],p0[12],p0[13],p0[14],p0[15]};
        const bf16x8 pa10 = {p1[0],p1[1],p1[2],p1[3],p1[4],p1[5],p1[6],p1[7]};
        const bf16x8 pa11 = {p1[8],p1[9],p1[10],p1[11],p1[12],p1[13],p1[14],p1[15]};
        acc0 = __builtin_amdgcn_mfma_f32_32x32x16_bf16(pa00, v0, acc0, 0, 0, 0);
        acc0 = __builtin_amdgcn_mfma_f32_32x32x16_bf16(pa01, v1, acc0, 0, 0, 0);
        acc1 = __builtin_amdgcn_mfma_f32_32x32x16_bf16(pa10, v0, acc1, 0, 0, 0);
        acc1 = __builtin_amdgcn_mfma_f32_32x32x16_bf16(pa11, v1, acc1, 0, 0, 0);
    };

    int kc = ksp * 1024;
    int it = 0;
    LD(kc, kfA, v0A, v1A);
    while (true) {
        if (it + 1 < 32) LD(kc + 32, kfB, v0B, v1B);
        COMP(kfA, v0A, v1A);
        kc += 32;
        if (++it >= 32) break;
        if (it + 1 < 32) LD(kc + 32, kfA, v0A, v1A);
        COMP(kfB, v0B, v1B);
        kc += 32;
        if (++it >= 32) break;
    }

    if (lm <= 16) {
        #pragma unroll
        for (int r = 0; r < 16; ++r) {
            const int qrow = (r & 3) + 8 * (r >> 2) + 4 * l5;
            smO[wid][qrow][lm]      = acc0[r];
            smO[wid][32 + qrow][lm] = acc1[r];
        }
    }
    __syncthreads();

    // 512 threads finalize 128q x 16d: combine 4 k-splits per q-group, normalize, residual
    const int q = tid >> 2;                  // 0..127
    const int d0 = (tid & 3) * 4;
    const int g4 = (q >> 6) * 4, ql = q & 63;
    const float ls = smO[g4][ql][16] + smO[g4+1][ql][16] + smO[g4+2][ql][16] + smO[g4+3][ql][16];
    const float ginv = gamma[layer] / ls;
    const int n = blockIdx.x * 128 + q;
    const int c0 = (h << 4) + d0;
    const short4 r4 = *reinterpret_cast<const short4*>(latbf + n * 128 + permpos(c0));
    short4 s4;
    #pragma unroll
    for (int dd = 0; dd < 4; ++dd) {
        const int d = d0 + dd;
        const float Ov = smO[g4][ql][d] + smO[g4+1][ql][d] + smO[g4+2][ql][d] + smO[g4+3][ql][d];
        const float val = Ov * ginv + bf2f(((const short*)&r4)[dd]);
        ((short*)&s4)[dd] = f2bf(val);
    }
    if (!last) {
        *reinterpret_cast<short4*>(latbf + n * 128 + permpos(c0)) = s4;
    } else {
        const int zq = n >> 8, yq = (n >> 4) & 15, xq = n & 15;
        const int vp = (zq + 1) * 324 + (yq + 1) * 18 + (xq + 1);
        *reinterpret_cast<short4*>(outbf + vp * 128 + permpos(c0)) = s4;
    }
}

// ---------------- conv2: LDS-halo MFMA. Block = 32co x 64vox, 4 waves ----------------
__global__ __launch_bounds__(256) void conv2_mfma(
    const short* __restrict__ xp,   // [5832][128perm]
    const short* __restrict__ wb,   // [27][128co][128perm]
    const float* __restrict__ bias,
    float* __restrict__ out)
{
    __shared__ short bl[324 * 136];  // 18 lines x 18 x (128+8) shorts = 88.1 KB
    const int tid = threadIdx.x;
    const int g = blockIdx.x;
    const int cot = g >> 6;          // 0..3
    const int vgrp = g & 63;
    const int r0 = vgrp * 4;
    const int z = r0 >> 4, y0 = r0 & 15;

    for (int i = tid; i < 5184; i += 256) {
        const int col = i >> 4, pc = i & 15;           // 324 cols x 16 pieces
        const int line = col / 18, xq = col - line * 18;
        const int dz = line / 6, yi = line - dz * 6;
        const int4 v = *reinterpret_cast<const int4*>(
            xp + (((z + dz) * 18 + (y0 + yi)) * 18 + xq) * 128 + pc * 8);
        const int slot = ((((pc >> 2) ^ col) & 3) << 5) + ((pc & 3) << 3);
        *reinterpret_cast<int4*>(&bl[col * 136 + slot]) = v;
    }
    __syncthreads();

    const int wid = tid >> 6, lane = tid & 63;
    const int lg = lane >> 4, lq = lane & 15;
    const int wc = wid >> 1, wv = wid & 1;
    const int co0 = cot * 32 + wc * 16;

    const short* pA = wb + (co0 + lq) * 128 + lg * 8;

    auto ldA = [&](int t, bf16x8* A) {
        const short* p = pA + t * 16384;
        #pragma unroll
        for (int c = 0; c < 4; ++c) A[c] = *reinterpret_cast<const bf16x8*>(p + c * 32);
    };

    f32x4 acc0 = {0.f,0.f,0.f,0.f}, acc1 = {0.f,0.f,0.f,0.f};

    auto comp = [&](int t, const bf16x8* A) {
        const int dz = t / 9, r9 = t - dz * 9, dy = r9 / 3, dx = r9 - dy * 3;
        #pragma unroll
        for (int ry = 0; ry < 2; ++ry) {
            const int col = (dz * 6 + wv * 2 + ry + dy) * 18 + dx + lq;
            const short* bp = &bl[col * 136 + (lg << 3)];
            #pragma unroll
            for (int c = 0; c < 4; ++c) {
                const bf16x8 b = *reinterpret_cast<const bf16x8*>(bp + (((c ^ col) & 3) << 5));
                if (ry == 0) acc0 = __builtin_amdgcn_mfma_f32_16x16x32_bf16(A[c], b, acc0, 0, 0, 0);
                else         acc1 = __builtin_amdgcn_mfma_f32_16x16x32_bf16(A[c], b, acc1, 0, 0, 0);
            }
        }
    };

    bf16x8 A0[4], A1[4];
    int t = 0;
    ldA(0, A0);
    while (true) {
        if (t + 1 < 27) ldA(t + 1, A1);
        comp(t, A0);
        if (++t >= 27) break;
        if (t + 1 < 27) ldA(t + 1, A0);
        comp(t, A1);
        if (++t >= 27) break;
    }

    #pragma unroll
    for (int ry = 0; ry < 2; ++ry) {
        const f32x4 a = ry ? acc1 : acc0;
        const int n = (r0 + wv * 2 + ry) * 16 + lq;
        #pragma unroll
        for (int i = 0; i < 4; ++i) {
            const int co = co0 + 4 * lg + i;
            out[co * NVOX + n] = a[i] + bias[co];
        }
    }
}

extern "C" void kernel_launch(void* const* d_in, const int* in_sizes, int n_in,
                              void* d_out, int out_size, void* d_ws, size_t ws_size,
                              hipStream_t stream) {
    const float* x     = (const float*)d_in[0];
    const float* lw    = (const float*)d_in[1];
    const float* lb    = (const float*)d_in[2];
    const float* pos   = (const float*)d_in[3];
    const float* qw    = (const float*)d_in[4];
    const float* qb    = (const float*)d_in[5];
    const float* kw    = (const float*)d_in[6];
    const float* kb    = (const float*)d_in[7];
    const float* vw    = (const float*)d_in[8];
    const float* vb    = (const float*)d_in[9];
    const float* gamma = (const float*)d_in[10];
    const float* ow    = (const float*)d_in[11];
    const float* ob    = (const float*)d_in[12];

    short* latbf = (short*)d_ws;                 // 524288 sh
    short* qP    = latbf + 524288;               // 524288 sh
    short* kP    = qP + 524288;                  // 524288 sh
    short* vP    = kP + 524288;                  // 557056 sh (8*17*4096)
    short* xpad  = vP + 557056;                  // 373248 sh (conv1 input)
    short* xpad2 = xpad + 373248;                // 746496 sh (conv2 input)
    short* wbf1  = xpad2 + 746496;               // 221184 sh
    short* wqkv  = wbf1 + 221184;                // 442368 sh
    short* wbf2  = wqkv + 442368;                // 442368 sh

    pack_all<<<4809, 256, 0, stream>>>(x, lw, qw, kw, vw, ow, xpad, wbf1, wqkv, wbf2, xpad2);

    conv1_mfma<<<256, 256, 0, stream>>>(xpad, wbf1, lb, pos, latbf);

    for (int i = 0; i < 3; ++i) {
        const int last = (i == 2);
        proj_mfma<<<dim3(32, 8, 3), 256, 0, stream>>>(
            latbf, wqkv + i * 49152, qb + i * 128, kb + i * 128, vb + i * 128, qP, kP, vP);
        attn_mfma<<<dim3(32, 8), 512, 0, stream>>>(
            qP, kP, vP, latbf, last ? xpad2 : latbf, gamma, i, last);
    }

    conv2_mfma<<<256, 256, 0, stream>>>(xpad2, wbf2, ob, (float*)d_out);
}

// Round 14
// 125.803 us; speedup vs baseline: 1.1255x; 1.0777x over previous
//
#include <hip/hip_runtime.h>
#include <hip/hip_bf16.h>

#define NVOX 4096   // 16*16*16
#define CDIM 128

typedef __attribute__((ext_vector_type(8)))  short bf16x8;
typedef __attribute__((ext_vector_type(4)))  float f32x4;
typedef __attribute__((ext_vector_type(16))) float f32x16;

static __device__ __forceinline__ short f2bf(float f) {
    __hip_bfloat16 h = __float2bfloat16(f);
    union { __hip_bfloat16 h; short s; } u; u.h = h; return u.s;
}
static __device__ __forceinline__ float bf2f(short s) {
    union { unsigned u; float f; } u;
    u.u = ((unsigned)(unsigned short)s) << 16;
    return u.f;
}
static __device__ __forceinline__ float fexp2(float x) {
    return __builtin_amdgcn_exp2f(x);
}
// MFMA K-fragment permutation for K=128 staging: packed position p <- channel ci
__device__ __forceinline__ int permpos(int ci) {
    return (((ci >> 2) & 3) << 3) + (ci & 3) + ((ci & 16) >> 2) + ((ci >> 5) << 5);
}
__device__ __forceinline__ int invp(int p) {
    const int c = p >> 5, r = p & 31, g = (r >> 3) & 3, j = r & 7;
    return (c << 5) + (j < 4 ? (g << 2) + j : 16 + (g << 2) + (j - 4));
}
// 16-element fragment permutation for 32x32x16 (K=16): pos(d)
__device__ __forceinline__ int pos16(int d) {
    return (d & 3) | ((d & 4) << 1) | ((d & 8) >> 1);
}

// ---------------- pack_all: weight/input packs + xpad2 zeroing, one launch ----------------
__global__ __launch_bounds__(256) void pack_all(
    const float* __restrict__ x,  const float* __restrict__ lw,
    const float* __restrict__ qw, const float* __restrict__ kw, const float* __restrict__ vw,
    const float* __restrict__ ow,
    short* __restrict__ xp, short* __restrict__ wb1, short* __restrict__ wqkv, short* __restrict__ wb2,
    short* __restrict__ xp2)
{
    const int b = blockIdx.x;
    const int tid = threadIdx.x;
    if (b < 1458) {                                   // pack_x
        const int e = b * 256 + tid;
        if (e >= 5832 * 64) return;
        const int vp = e >> 6, p = e & 63;
        const int z = vp / 324, rem = vp - z * 324, y = rem / 18, xx = rem % 18;
        short val = 0;
        if (z >= 1 && z <= 16 && y >= 1 && y <= 16 && xx >= 1 && xx <= 16) {
            const int n = ((z - 1) * 16 + (y - 1)) * 16 + (xx - 1);
            val = f2bf(x[invp(p) * NVOX + n]);
        }
        xp[e] = val;
    } else if (b < 1458 + 864) {                      // pack_w1
        const int e = (b - 1458) * 256 + tid;
        if (e >= 27 * 128 * 64) return;
        const int t = e >> 13, co = (e >> 6) & 127, p = e & 63;
        wb1[e] = f2bf(lw[(co * 64 + invp(p)) * 27 + t]);
    } else if (b < 1458 + 864 + 576) {                // pack_wqkv
        const int e = (b - 2322) * 256 + tid;
        if (e >= 3 * 3 * 128 * 128) return;
        const int l = e / 49152, r = e - l * 49152;
        const int m = r >> 14, co = (r >> 7) & 127, p = r & 127;
        const float* W = (m == 0 ? qw : m == 1 ? kw : vw) + l * 16384;
        wqkv[e] = f2bf(W[co * 128 + invp(p)]);
    } else if (b < 1458 + 864 + 576 + 1728) {         // pack_w2
        const int e = (b - 2898) * 256 + tid;
        if (e >= 27 * 128 * 128) return;
        const int t = e >> 14, co = (e >> 7) & 127, p = e & 127;
        wb2[e] = f2bf(ow[(invp(p) * 128 + co) * 27 + (26 - t)]);
    } else {                                          // zero xpad2 (borders; interior rewritten by attn L2)
        const int e = (b - 4626) * 256 + tid;
        if (e >= 5832 * 16) return;
        const int4 z4 = {0, 0, 0, 0};
        *reinterpret_cast<int4*>(xp2 + e * 8) = z4;
    }
}

// ---------------- conv1: LDS-halo MFMA. Block = 32co x 64vox, 4 waves ----------------
__global__ __launch_bounds__(256) void conv1_mfma(
    const short* __restrict__ xp,   // [5832][64perm]
    const short* __restrict__ wb,   // [27][128][64perm]
    const float* __restrict__ bias, const float* __restrict__ pos,
    short* __restrict__ latbf)
{
    __shared__ short bl[324 * 72];  // 18 lines x 18 x (64+8) shorts = 46.6 KB
    const int tid = threadIdx.x;
    const int g = blockIdx.x;
    const int cot = g >> 6;          // 0..3
    const int vgrp = g & 63;
    const int r0 = vgrp * 4;
    const int z = r0 >> 4, y0 = r0 & 15;

    for (int i = tid; i < 2592; i += 256) {
        const int col = i >> 3, pc = i & 7;            // 324 cols x 8 pieces
        const int line = col / 18, xq = col - line * 18;
        const int dz = line / 6, yi = line - dz * 6;
        const int4 v = *reinterpret_cast<const int4*>(
            xp + (((z + dz) * 18 + (y0 + yi)) * 18 + xq) * 64 + pc * 8);
        const int slot = ((((pc >> 2) ^ col) & 1) << 5) + ((pc & 3) << 3);
        *reinterpret_cast<int4*>(&bl[col * 72 + slot]) = v;
    }
    __syncthreads();

    const int wid = tid >> 6, lane = tid & 63;
    const int lg = lane >> 4, lq = lane & 15;
    const int wc = wid >> 1, wv = wid & 1;
    const int co0 = cot * 32 + wc * 16;

    const short* pA = wb + (co0 + lq) * 64 + lg * 8;

    auto ldA = [&](int t, bf16x8* A) {
        const short* p = pA + t * 8192;
        #pragma unroll
        for (int c = 0; c < 2; ++c) A[c] = *reinterpret_cast<const bf16x8*>(p + c * 32);
    };

    f32x4 acc0 = {0.f,0.f,0.f,0.f}, acc1 = {0.f,0.f,0.f,0.f};

    auto comp = [&](int t, const bf16x8* A) {
        const int dz = t / 9, r9 = t - dz * 9, dy = r9 / 3, dx = r9 - dy * 3;
        #pragma unroll
        for (int ry = 0; ry < 2; ++ry) {
            const int col = (dz * 6 + wv * 2 + ry + dy) * 18 + dx + lq;
            const short* bp = &bl[col * 72 + (lg << 3)];
            #pragma unroll
            for (int c = 0; c < 2; ++c) {
                const bf16x8 b = *reinterpret_cast<const bf16x8*>(bp + (((c ^ col) & 1) << 5));
                if (ry == 0) acc0 = __builtin_amdgcn_mfma_f32_16x16x32_bf16(A[c], b, acc0, 0, 0, 0);
                else         acc1 = __builtin_amdgcn_mfma_f32_16x16x32_bf16(A[c], b, acc1, 0, 0, 0);
            }
        }
    };

    bf16x8 A0[2], A1[2];
    int t = 0;
    ldA(0, A0);
    while (true) {
        if (t + 1 < 27) ldA(t + 1, A1);
        comp(t, A0);
        if (++t >= 27) break;
        if (t + 1 < 27) ldA(t + 1, A0);
        comp(t, A1);
        if (++t >= 27) break;
    }

    #pragma unroll
    for (int ry = 0; ry < 2; ++ry) {
        const f32x4 a = ry ? acc1 : acc0;
        const int n = (r0 + wv * 2 + ry) * 16 + lq;
        short4 s4;
        #pragma unroll
        for (int i = 0; i < 4; ++i) {
            const int co = co0 + 4 * lg + i;
            const float v = a[i] + bias[co] + pos[co * NVOX + n];
            ((short*)&s4)[i] = f2bf(v);
        }
        *reinterpret_cast<short4*>(latbf + n * 128 + permpos(co0 + 4 * lg)) = s4;
    }
}

// ---------------- proj: 3x GEMM 128x4096x128; A in regs, 2 row-tiles/wave ----------------
__global__ __launch_bounds__(256) void proj_mfma(
    const short* __restrict__ latbf,     // [4096][128perm]
    const short* __restrict__ wl,        // [3][128][128perm] (this layer)
    const float* __restrict__ bq, const float* __restrict__ bk, const float* __restrict__ bv,
    short* __restrict__ qP, short* __restrict__ kP, short* __restrict__ vP)
{
    const int m = blockIdx.z;
    const int wid = threadIdx.x >> 6, lane = threadIdx.x & 63;
    const int lg = lane >> 4, lq = lane & 15;
    const int co0 = blockIdx.y * 16;
    const int row0 = (blockIdx.x * 4 + wid) * 2;

    const short* A = wl + m * 16384 + (co0 + lq) * 128 + lg * 8;
    bf16x8 Af[4];
    #pragma unroll
    for (int c = 0; c < 4; ++c) Af[c] = *reinterpret_cast<const bf16x8*>(A + c * 32);

    const short* Bp0 = latbf + (row0 * 16 + lq) * 128 + lg * 8;
    const short* Bp1 = Bp0 + 16 * 128;
    bf16x8 Bf0[4], Bf1[4];
    #pragma unroll
    for (int c = 0; c < 4; ++c) Bf0[c] = *reinterpret_cast<const bf16x8*>(Bp0 + c * 32);
    #pragma unroll
    for (int c = 0; c < 4; ++c) Bf1[c] = *reinterpret_cast<const bf16x8*>(Bp1 + c * 32);

    f32x4 a0a = {0.f,0.f,0.f,0.f}, a0b = a0a, a1a = a0a, a1b = a0a;
    a0a = __builtin_amdgcn_mfma_f32_16x16x32_bf16(Af[0], Bf0[0], a0a, 0, 0, 0);
    a1a = __builtin_amdgcn_mfma_f32_16x16x32_bf16(Af[0], Bf1[0], a1a, 0, 0, 0);
    a0b = __builtin_amdgcn_mfma_f32_16x16x32_bf16(Af[1], Bf0[1], a0b, 0, 0, 0);
    a1b = __builtin_amdgcn_mfma_f32_16x16x32_bf16(Af[1], Bf1[1], a1b, 0, 0, 0);
    a0a = __builtin_amdgcn_mfma_f32_16x16x32_bf16(Af[2], Bf0[2], a0a, 0, 0, 0);
    a1a = __builtin_amdgcn_mfma_f32_16x16x32_bf16(Af[2], Bf1[2], a1a, 0, 0, 0);
    a0b = __builtin_amdgcn_mfma_f32_16x16x32_bf16(Af[3], Bf0[3], a0b, 0, 0, 0);
    a1b = __builtin_amdgcn_mfma_f32_16x16x32_bf16(Af[3], Bf1[3], a1b, 0, 0, 0);

    const int h = blockIdx.y;
    #pragma unroll
    for (int rr = 0; rr < 2; ++rr) {
        const f32x4 acc = rr ? (a1a + a1b) : (a0a + a0b);
        const int row = row0 + rr;
        const int n = row * 16 + lq;
        if (m == 2) {
            const int col = row * 16 + pos16(lq);
            #pragma unroll
            for (int r = 0; r < 4; ++r) {
                const int d = lg * 4 + r;
                vP[(h * 17 + d) * NVOX + col] = f2bf(acc[r] + bv[co0 + d]);
            }
            if (lg == 0) vP[(h * 17 + 16) * NVOX + col] = (short)0x3F80;  // bf16 1.0
        } else {
            const float* bias = (m == 0) ? bq : bk;
            const float S = (m == 0) ? 0.25f * 1.4426950408889634f : 1.f;
            const int pg = ((lg & 1) << 3) | ((lg & 2) << 1);   // pos16(lg*4)
            short4 s4;
            #pragma unroll
            for (int r = 0; r < 4; ++r) {
                const int co = co0 + lg * 4 + r;
                ((short*)&s4)[r] = f2bf((acc[r] + bias[co]) * S);
            }
            short* dst = (m == 0) ? qP : kP;
            *reinterpret_cast<short4*>(dst + ((h << 12) + n) * 16 + pg) = s4;
        }
    }
}

// ---------------- attn: 32x32x16 MFMA, no-max softmax, 8 waves = 2 qgrp x 4 ksplit ----------------
__global__ __launch_bounds__(512) void attn_mfma(
    const short* __restrict__ qP, const short* __restrict__ kP, const short* __restrict__ vP,
    short* __restrict__ latbf, short* __restrict__ outbf,
    const float* __restrict__ gamma, int layer, int last)
{
    __shared__ float smO[8][64][17];
    const int tid = threadIdx.x;
    const int wid = tid >> 6, lane = tid & 63;
    const int l5 = lane >> 5, lm = lane & 31;
    const int qg = wid >> 2, ksp = wid & 3;
    const int h = blockIdx.y;
    const int qbase = blockIdx.x * 128 + qg * 64;

    const bf16x8 qf0 = *reinterpret_cast<const bf16x8*>(
        qP + (((h << 12) + qbase + lm) << 4) + l5 * 8);
    const bf16x8 qf1 = *reinterpret_cast<const bf16x8*>(
        qP + (((h << 12) + qbase + 32 + lm) << 4) + l5 * 8);

    const short* kbase = kP + (((size_t)h) << 16);       // h*4096*16
    const int vrow = (lm & 16) ? 16 : lm;
    const short* vbase = vP + ((size_t)h * 17 + vrow) * NVOX + l5 * 8;

    f32x16 acc0 = {0.f,0.f,0.f,0.f,0.f,0.f,0.f,0.f,0.f,0.f,0.f,0.f,0.f,0.f,0.f,0.f};
    f32x16 acc1 = acc0;
    const f32x16 zero = acc0;

    bf16x8 kfA, v0A, v1A, kfB, v0B, v1B;
    auto LD = [&](int kc, bf16x8& kf, bf16x8& v0, bf16x8& v1) {
        kf = *reinterpret_cast<const bf16x8*>(kbase + ((kc + lm) << 4) + l5 * 8);
        v0 = *reinterpret_cast<const bf16x8*>(vbase + kc);
        v1 = *reinterpret_cast<const bf16x8*>(vbase + kc + 16);
    };
    auto COMP = [&](const bf16x8& kf, const bf16x8& v0, const bf16x8& v1) {
        const f32x16 S0 = __builtin_amdgcn_mfma_f32_32x32x16_bf16(kf, qf0, zero, 0, 0, 0);
        const f32x16 S1 = __builtin_amdgcn_mfma_f32_32x32x16_bf16(kf, qf1, zero, 0, 0, 0);
        short p0[16], p1[16];
        #pragma unroll
        for (int r = 0; r < 16; ++r) p0[r] = f2bf(fexp2(S0[r]));
        #pragma unroll
        for (int r = 0; r < 16; ++r) p1[r] = f2bf(fexp2(S1[r]));
        const bf16x8 pa00 = {p0[0],p0[1],p0[2],p0[3],p0[4],p0[5],p0[6],p0[7]};
        const bf16x8 pa01 = {p0[8],p0[9],p0[10],p0[11],p0[12],p0[13],p0[14],p0[15]};
        const bf16x8 pa10 = {p1[0],p1[1],p1[2],p1[3],p1[4],p1[5],p1[6],p1[7]};
        const bf16x8 pa11 = {p1[8],p1[9],p1[10],p1[11],p1[12],p1[13],p1[14],p1[15]};
        acc0 = __builtin_amdgcn_mfma_f32_32x32x16_bf16(pa00, v0, acc0, 0, 0, 0);
        acc0 = __builtin_amdgcn_mfma_f32_32x32x16_bf16(pa01, v1, acc0, 0, 0, 0);
        acc1 = __builtin_amdgcn_mfma_f32_32x32x16_bf16(pa10, v0, acc1, 0, 0, 0);
        acc1 = __builtin_amdgcn_mfma_f32_32x32x16_bf16(pa11, v1, acc1, 0, 0, 0);
    };

    int kc = ksp * 1024;
    int it = 0;
    LD(kc, kfA, v0A, v1A);
    while (true) {
        if (it + 1 < 32) LD(kc + 32, kfB, v0B, v1B);
        COMP(kfA, v0A, v1A);
        kc += 32;
        if (++it >= 32) break;
        if (it + 1 < 32) LD(kc + 32, kfA, v0A, v1A);
        COMP(kfB, v0B, v1B);
        kc += 32;
        if (++it >= 32) break;
    }

    if (lm <= 16) {
        #pragma unroll
        for (int r = 0; r < 16; ++r) {
            const int qrow = (r & 3) + 8 * (r >> 2) + 4 * l5;
            smO[wid][qrow][lm]      = acc0[r];
            smO[wid][32 + qrow][lm] = acc1[r];
        }
    }
    __syncthreads();

    // 512 threads finalize 128q x 16d: combine 4 k-splits per q-group, normalize, residual
    const int q = tid >> 2;                  // 0..127
    const int d0 = (tid & 3) * 4;
    const int g4 = (q >> 6) * 4, ql = q & 63;
    const float ls = smO[g4][ql][16] + smO[g4+1][ql][16] + smO[g4+2][ql][16] + smO[g4+3][ql][16];
    const float ginv = gamma[layer] / ls;
    const int n = blockIdx.x * 128 + q;
    const int c0 = (h << 4) + d0;
    const short4 r4 = *reinterpret_cast<const short4*>(latbf + n * 128 + permpos(c0));
    short4 s4;
    #pragma unroll
    for (int dd = 0; dd < 4; ++dd) {
        const int d = d0 + dd;
        const float Ov = smO[g4][ql][d] + smO[g4+1][ql][d] + smO[g4+2][ql][d] + smO[g4+3][ql][d];
        const float val = Ov * ginv + bf2f(((const short*)&r4)[dd]);
        ((short*)&s4)[dd] = f2bf(val);
    }
    if (!last) {
        *reinterpret_cast<short4*>(latbf + n * 128 + permpos(c0)) = s4;
    } else {
        const int zq = n >> 8, yq = (n >> 4) & 15, xq = n & 15;
        const int vp = (zq + 1) * 324 + (yq + 1) * 18 + (xq + 1);
        *reinterpret_cast<short4*>(outbf + vp * 128 + permpos(c0)) = s4;
    }
}

// ---------------- conv2: LDS-halo MFMA. Block = 32co x 64vox, 4 waves ----------------
__global__ __launch_bounds__(256) void conv2_mfma(
    const short* __restrict__ xp,   // [5832][128perm]
    const short* __restrict__ wb,   // [27][128co][128perm]
    const float* __restrict__ bias,
    float* __restrict__ out)
{
    __shared__ short bl[324 * 136];  // 18 lines x 18 x (128+8) shorts = 88.1 KB
    const int tid = threadIdx.x;
    const int g = blockIdx.x;
    const int cot = g >> 6;          // 0..3
    const int vgrp = g & 63;
    const int r0 = vgrp * 4;
    const int z = r0 >> 4, y0 = r0 & 15;

    for (int i = tid; i < 5184; i += 256) {
        const int col = i >> 4, pc = i & 15;           // 324 cols x 16 pieces
        const int line = col / 18, xq = col - line * 18;
        const int dz = line / 6, yi = line - dz * 6;
        const int4 v = *reinterpret_cast<const int4*>(
            xp + (((z + dz) * 18 + (y0 + yi)) * 18 + xq) * 128 + pc * 8);
        const int slot = ((((pc >> 2) ^ col) & 3) << 5) + ((pc & 3) << 3);
        *reinterpret_cast<int4*>(&bl[col * 136 + slot]) = v;
    }
    __syncthreads();

    const int wid = tid >> 6, lane = tid & 63;
    const int lg = lane >> 4, lq = lane & 15;
    const int wc = wid >> 1, wv = wid & 1;
    const int co0 = cot * 32 + wc * 16;

    const short* pA = wb + (co0 + lq) * 128 + lg * 8;

    auto ldA = [&](int t, bf16x8* A) {
        const short* p = pA + t * 16384;
        #pragma unroll
        for (int c = 0; c < 4; ++c) A[c] = *reinterpret_cast<const bf16x8*>(p + c * 32);
    };

    f32x4 acc0 = {0.f,0.f,0.f,0.f}, acc1 = {0.f,0.f,0.f,0.f};

    auto comp = [&](int t, const bf16x8* A) {
        const int dz = t / 9, r9 = t - dz * 9, dy = r9 / 3, dx = r9 - dy * 3;
        #pragma unroll
        for (int ry = 0; ry < 2; ++ry) {
            const int col = (dz * 6 + wv * 2 + ry + dy) * 18 + dx + lq;
            const short* bp = &bl[col * 136 + (lg << 3)];
            #pragma unroll
            for (int c = 0; c < 4; ++c) {
                const bf16x8 b = *reinterpret_cast<const bf16x8*>(bp + (((c ^ col) & 3) << 5));
                if (ry == 0) acc0 = __builtin_amdgcn_mfma_f32_16x16x32_bf16(A[c], b, acc0, 0, 0, 0);
                else         acc1 = __builtin_amdgcn_mfma_f32_16x16x32_bf16(A[c], b, acc1, 0, 0, 0);
            }
        }
    };

    bf16x8 A0[4], A1[4];
    int t = 0;
    ldA(0, A0);
    while (true) {
        if (t + 1 < 27) ldA(t + 1, A1);
        comp(t, A0);
        if (++t >= 27) break;
        if (t + 1 < 27) ldA(t + 1, A0);
        comp(t, A1);
        if (++t >= 27) break;
    }

    #pragma unroll
    for (int ry = 0; ry < 2; ++ry) {
        const f32x4 a = ry ? acc1 : acc0;
        const int n = (r0 + wv * 2 + ry) * 16 + lq;
        #pragma unroll
        for (int i = 0; i < 4; ++i) {
            const int co = co0 + 4 * lg + i;
            out[co * NVOX + n] = a[i] + bias[co];
        }
    }
}

extern "C" void kernel_launch(void* const* d_in, const int* in_sizes, int n_in,
                              void* d_out, int out_size, void* d_ws, size_t ws_size,
                              hipStream_t stream) {
    const float* x     = (const float*)d_in[0];
    const float* lw    = (const float*)d_in[1];
    const float* lb    = (const float*)d_in[2];
    const float* pos   = (const float*)d_in[3];
    const float* qw    = (const float*)d_in[4];
    const float* qb    = (const float*)d_in[5];
    const float* kw    = (const float*)d_in[6];
    const float* kb    = (const float*)d_in[7];
    const float* vw    = (const float*)d_in[8];
    const float* vb    = (const float*)d_in[9];
    const float* gamma = (const float*)d_in[10];
    const float* ow    = (const float*)d_in[11];
    const float* ob    = (const float*)d_in[12];

    short* latbf = (short*)d_ws;                 // 524288 sh
    short* qP    = latbf + 524288;               // 524288 sh
    short* kP    = qP + 524288;                  // 524288 sh
    short* vP    = kP + 524288;                  // 557056 sh (8*17*4096)
    short* xpad  = vP + 557056;                  // 373248 sh (conv1 input)
    short* xpad2 = xpad + 373248;                // 746496 sh (conv2 input)
    short* wbf1  = xpad2 + 746496;               // 221184 sh
    short* wqkv  = wbf1 + 221184;                // 442368 sh
    short* wbf2  = wqkv + 442368;                // 442368 sh

    pack_all<<<4809, 256, 0, stream>>>(x, lw, qw, kw, vw, ow, xpad, wbf1, wqkv, wbf2, xpad2);

    conv1_mfma<<<256, 256, 0, stream>>>(xpad, wbf1, lb, pos, latbf);

    for (int i = 0; i < 3; ++i) {
        const int last = (i == 2);
        proj_mfma<<<dim3(32, 8, 3), 256, 0, stream>>>(
            latbf, wqkv + i * 49152, qb + i * 128, kb + i * 128, vb + i * 128, qP, kP, vP);
        attn_mfma<<<dim3(32, 8), 512, 0, stream>>>(
            qP, kP, vP, latbf, last ? xpad2 : latbf, gamma, i, last);
    }

    conv2_mfma<<<256, 256, 0, stream>>>(xpad2, wbf2, ob, (float*)d_out);
}